// Round 16
// baseline (115.528 us; speedup 1.0000x reference)
//
#include <hip/hip_runtime.h>
#include <hip/hip_bf16.h>
#include <stdint.h>

// ALBEF contrastive loss: B=256, Q=32, L=40, VW=TW=768, D=256.
// S = sim_i2t/temp; sim_t2i = S^T, so loss = row-LSE + col-LSE of one S.

using f32x4  = __attribute__((ext_vector_type(4))) float;
using bf16x8 = __attribute__((ext_vector_type(8))) short;
typedef unsigned uint32x2 __attribute__((ext_vector_type(2)));

__device__ __forceinline__ short f2bf(float f) {
  union { float f; uint32_t u; } x; x.f = f;
  uint32_t r = x.u + 0x7FFFu + ((x.u >> 16) & 1u);  // RNE
  return (short)(r >> 16);
}

// pack 8 f32 -> 8 bf16 via v_cvt_pk_bf16_f32 (RNE, 2 elems/instr)
__device__ __forceinline__ bf16x8 pack8pk(float4 v0, float4 v1) {
  union { uint32_t u[4]; bf16x8 v; } r;
  asm("v_cvt_pk_bf16_f32 %0, %1, %2" : "=v"(r.u[0]) : "v"(v0.x), "v"(v0.y));
  asm("v_cvt_pk_bf16_f32 %0, %1, %2" : "=v"(r.u[1]) : "v"(v0.z), "v"(v0.w));
  asm("v_cvt_pk_bf16_f32 %0, %1, %2" : "=v"(r.u[2]) : "v"(v1.x), "v"(v1.y));
  asm("v_cvt_pk_bf16_f32 %0, %1, %2" : "=v"(r.u[3]) : "v"(v1.z), "v"(v1.w));
  return r.v;
}

// async global->LDS, 16B per lane; LDS dest = wave-uniform base + lane*16
__device__ __forceinline__ void gl_lds16(const unsigned short* g, unsigned short* l) {
  __builtin_amdgcn_global_load_lds(
      (const __attribute__((address_space(1))) void*)g,
      (__attribute__((address_space(3))) void*)l, 16, 0, 0);
}

// ---- DPP lane reductions (VALU pipe, not LDS) ----
template <int CTRL>
__device__ __forceinline__ float dppf(float x) {
  return __int_as_float(__builtin_amdgcn_update_dpp(
      0, __float_as_int(x), CTRL, 0xF, 0xF, true));
}
__device__ __forceinline__ float max16(float x) {  // max over 16-lane row
  x = fmaxf(x, dppf<0xB1>(x));
  x = fmaxf(x, dppf<0x4E>(x));
  x = fmaxf(x, dppf<0x141>(x));
  x = fmaxf(x, dppf<0x140>(x));
  return x;
}
__device__ __forceinline__ float sum16(float x) {  // sum over 16-lane row
  x += dppf<0xB1>(x);
  x += dppf<0x4E>(x);
  x += dppf<0x141>(x);
  x += dppf<0x140>(x);
  return x;
}
// row-uniform input -> lane 63 holds sum of the 4 row values (VALU only)
__device__ __forceinline__ float rowsum_to63(float x) {
  x += dppf<0x142>(x);   // ROW_BCAST15
  x += dppf<0x143>(x);   // ROW_BCAST31
  return x;              // lane 63 = r0+r1+r2+r3
}

// ---- cross-row element-wise combines on the VALU pipe (gfx950 permlane) ----
#if __has_builtin(__builtin_amdgcn_permlane16_swap)
__device__ __forceinline__ float plmax16(float x) {
  uint32x2 r = __builtin_amdgcn_permlane16_swap(__float_as_uint(x), __float_as_uint(x), false, false);
  return fmaxf(__uint_as_float(r[0]), __uint_as_float(r[1]));
}
#else
__device__ __forceinline__ float plmax16(float x) { return fmaxf(x, __shfl_xor(x, 16)); }
#endif
#if __has_builtin(__builtin_amdgcn_permlane32_swap)
__device__ __forceinline__ float plmax32(float x) {
  uint32x2 r = __builtin_amdgcn_permlane32_swap(__float_as_uint(x), __float_as_uint(x), false, false);
  return fmaxf(__uint_as_float(r[0]), __uint_as_float(r[1]));
}
#else
__device__ __forceinline__ float plmax32(float x) { return fmaxf(x, __shfl_xor(x, 32)); }
#endif

// ------------- W transpose+cvt via LDS tiles + mask preprocess (block 0) ----
__global__ __launch_bounds__(256) void k_trw(const float* __restrict__ Wc,
                                             const float* __restrict__ Ww,
                                             const int* __restrict__ tm,
                                             unsigned short* __restrict__ Wct,
                                             unsigned short* __restrict__ Wwt,
                                             unsigned long long* __restrict__ mb,
                                             float* __restrict__ nw) {
  __shared__ float tile[32][33];
  if (blockIdx.x == 0) {
    int b = threadIdx.x;  // 256 threads, one per batch row
    unsigned long long bits = 0ull;
    int sep = -1;
    #pragma unroll
    for (int t = 1; t < 40; ++t) {
      if (tm[b * 40 + t] > 0) { bits |= (1ull << t); sep = t; }
    }
    if (sep >= 0) bits &= ~(1ull << sep);
    mb[b] = bits;
    nw[b] = 1.0f / (float)__popcll(bits);
  }
  int blk = blockIdx.x;
  const float* W; unsigned short* O;
  if (blk < 192) { W = Wc; O = Wct; } else { W = Ww; O = Wwt; blk -= 192; }
  const int tk = blk >> 3, td = blk & 7;   // 24 k-tiles x 8 d-tiles
  const int k0 = tk * 32, d0 = td * 32;
  const int t = threadIdx.x;
  const int r = t >> 3, cq = (t & 7) * 4;
  float4 v = *(const float4*)(W + (size_t)(k0 + r) * 256 + d0 + cq);
  tile[r][cq] = v.x; tile[r][cq + 1] = v.y; tile[r][cq + 2] = v.z; tile[r][cq + 3] = v.w;
  __syncthreads();
  ushort4 o;
  o.x = (unsigned short)f2bf(tile[cq + 0][r]);
  o.y = (unsigned short)f2bf(tile[cq + 1][r]);
  o.z = (unsigned short)f2bf(tile[cq + 2][r]);
  o.w = (unsigned short)f2bf(tile[cq + 3][r]);
  *(ushort4*)(O + (size_t)(d0 + r) * 768 + k0 + cq) = o;
}

// ---------- merged proj GEMM + bias + l2norm, LDS-staged A -----------------
__global__ __launch_bounds__(256) void k_proj(const float* __restrict__ Xc,
                                              const float* __restrict__ Xt,
                                              const unsigned short* __restrict__ Wct,
                                              const unsigned short* __restrict__ Wwt,
                                              const float* __restrict__ bc,
                                              const float* __restrict__ bw,
                                              unsigned short* __restrict__ CFb,
                                              unsigned short* __restrict__ WFb) {
  __shared__ unsigned short As[32 * 768];  // 48 KB bf16, swizzled
  __shared__ float red[32][4];
  const int blk = blockIdx.x;
  const float* X; const unsigned short* Wtb; const float* bias;
  unsigned short* out; int m0;
  if (blk < 256) { X = Xc; Wtb = Wct; bias = bc; out = CFb; m0 = blk * 32; }
  else           { X = Xt; Wtb = Wwt; bias = bw; out = WFb; m0 = (blk - 256) * 32; }

  const int t = threadIdx.x;
  #pragma unroll
  for (int i = 0; i < 12; ++i) {
    int ch = i * 256 + t;
    int r = ch / 96, c = ch - r * 96;
    const float* p = X + (size_t)(m0 + r) * 768 + c * 8;
    bf16x8 v = pack8pk(*(const float4*)p, *(const float4*)(p + 4));
    *(bf16x8*)(&As[r * 768 + ((c ^ (r & 7)) * 8)]) = v;
  }
  __syncthreads();

  const int w = t >> 6, l = t & 63;
  const int lr = l & 15, lg = l >> 4;
  const int n0 = w * 64;

  f32x4 acc[2][4];
  #pragma unroll
  for (int mi = 0; mi < 2; ++mi)
    #pragma unroll
    for (int ni = 0; ni < 4; ++ni) acc[mi][ni] = f32x4{0.f, 0.f, 0.f, 0.f};

  const int r0 = lr, r1 = 16 + lr;

  #pragma unroll 4
  for (int ks = 0; ks < 24; ++ks) {
    const int c16 = ks * 4 + lg;
    bf16x8 a0 = *(const bf16x8*)(&As[r0 * 768 + ((c16 ^ (r0 & 7)) * 8)]);
    bf16x8 a1 = *(const bf16x8*)(&As[r1 * 768 + ((c16 ^ (r1 & 7)) * 8)]);
    bf16x8 bb[4];
    #pragma unroll
    for (int ni = 0; ni < 4; ++ni)
      bb[ni] = *(const bf16x8*)(Wtb + (size_t)(n0 + ni * 16 + lr) * 768 + ks * 32 + lg * 8);
    #pragma unroll
    for (int ni = 0; ni < 4; ++ni)
      acc[0][ni] = __builtin_amdgcn_mfma_f32_16x16x32_bf16(a0, bb[ni], acc[0][ni], 0, 0, 0);
    #pragma unroll
    for (int ni = 0; ni < 4; ++ni)
      acc[1][ni] = __builtin_amdgcn_mfma_f32_16x16x32_bf16(a1, bb[ni], acc[1][ni], 0, 0, 0);
  }

  float bv[4];
  #pragma unroll
  for (int ni = 0; ni < 4; ++ni) bv[ni] = bias[n0 + ni * 16 + lr];

  float ss[2][4];
  #pragma unroll
  for (int mi = 0; mi < 2; ++mi)
    #pragma unroll
    for (int j = 0; j < 4; ++j) {
      float s = 0.f;
      #pragma unroll
      for (int ni = 0; ni < 4; ++ni) {
        acc[mi][ni][j] += bv[ni];
        s += acc[mi][ni][j] * acc[mi][ni][j];
      }
      ss[mi][j] = s;
    }
  #pragma unroll
  for (int m = 1; m <= 8; m <<= 1)
    #pragma unroll
    for (int mi = 0; mi < 2; ++mi)
      #pragma unroll
      for (int j = 0; j < 4; ++j)
        ss[mi][j] += __shfl_xor(ss[mi][j], m);
  if (lr == 0) {
    #pragma unroll
    for (int mi = 0; mi < 2; ++mi)
      #pragma unroll
      for (int j = 0; j < 4; ++j)
        red[mi * 16 + lg * 4 + j][w] = ss[mi][j];
  }
  __syncthreads();
  #pragma unroll
  for (int mi = 0; mi < 2; ++mi)
    #pragma unroll
    for (int j = 0; j < 4; ++j) {
      int r = mi * 16 + lg * 4 + j;
      float sc = rsqrtf(red[r][0] + red[r][1] + red[r][2] + red[r][3]);
      #pragma unroll
      for (int ni = 0; ni < 4; ++ni)
        out[(size_t)(m0 + r) * 256 + n0 + ni * 16 + lr] =
            (unsigned short)f2bf(acc[mi][ni][j] * sc);
    }
}

// ------------- pairwise sim: 16 b x 16 c per block, 2 b's per wave ---------
// 512 threads (8 waves), grid (16,16)=256 blocks. 16 c's as 4 sequential
// 4-c panels staged into one 80KB LDS buffer. Valid tokens are contiguous
// [1,len-2], so per-c block-uniform flags gate entire ni blocks:
//   has1 (len>=18, ~70%): tokens in t=[16,32)   has2 (len>=34, ~21%): t>=32.
// Skipped blocks leave acc==0 and val[ni] all-false -> tail math unchanged.
// The tail's cp[1]/cp[2] DPP chains are gated by the same flags.
__global__ __launch_bounds__(512, 2) void k_pair(const unsigned short* __restrict__ CF,
                                                 const unsigned short* __restrict__ WF,
                                                 const unsigned long long* __restrict__ MB,
                                                 const float* __restrict__ NW,
                                                 const float* __restrict__ TEMP,
                                                 float* __restrict__ S,
                                                 float* __restrict__ St) {
  __shared__ unsigned short wfs[40960];  // 4 tiles x [40][256] bf16, swizzled
  const int tid = threadIdx.x;
  const int w = tid >> 6, l = tid & 63;
  const int lr = l & 15, lg = l >> 4;
  const int b0 = blockIdx.x * 16, c0 = blockIdx.y * 16;
  const float invt = 1.0f / TEMP[0];
  const float s32 = invt * 0.03125f;

  // stage panel: 8 waves; wave w stages tile (w>>1) half (w&1): 10 x 1KB
  const int sti = w >> 1, sth = w & 1;
  {
    const int cq = c0;
    #pragma unroll
    for (int j = 0; j < 10; ++j) {
      int t = sth * 20 + j * 2 + (l >> 5), sl = l & 31;
      gl_lds16(WF + ((size_t)(cq + sti) * 40 + t) * 256 + ((sl ^ (t & 7)) * 8),
               &wfs[sti * 10240 + sth * 5120 + j * 512]);
    }
  }

  // hoist A frags for this wave's two b's (L2-resident CF): 128 VGPRs
  bf16x8 a[2][2][8];
  #pragma unroll
  for (int bi = 0; bi < 2; ++bi) {
    const int b = b0 + w * 2 + bi;
    #pragma unroll
    for (int mi = 0; mi < 2; ++mi)
      #pragma unroll
      for (int ks = 0; ks < 8; ++ks)
        a[bi][mi][ks] = *(const bf16x8*)(CF + (size_t)(b * 32 + mi * 16 + lr) * 256 + (ks * 4 + lg) * 8);
  }

  // 6 swizzled LDS base offsets (bytes); per-read immediate = k*128 + ci*20480.
  int lbase[3][2];
  #pragma unroll
  for (int ni = 0; ni < 3; ++ni) {
    int t = ni * 16 + lr; if (t > 39) t = 39;
    int x = t & 7;
    #pragma unroll
    for (int p = 0; p < 2; ++p)
      lbase[ni][p] = t * 512 + ((lg ^ (x & 3)) * 16) + ((p ^ ((x >> 2) & 1)) * 64);
  }
  const char* ldsb = (const char*)wfs;

  asm volatile("s_waitcnt vmcnt(0)" ::: "memory");
  __syncthreads();

  #pragma unroll 1
  for (int pn = 0; pn < 4; ++pn) {
    const int cq = c0 + pn * 4;
    if (pn > 0) {
      __syncthreads();   // all waves done reading previous panel
      #pragma unroll
      for (int j = 0; j < 10; ++j) {
        int t = sth * 20 + j * 2 + (l >> 5), sl = l & 31;
        gl_lds16(WF + ((size_t)(cq + sti) * 40 + t) * 256 + ((sl ^ (t & 7)) * 8),
                 &wfs[sti * 10240 + sth * 5120 + j * 512]);
      }
      asm volatile("s_waitcnt vmcnt(0)" ::: "memory");
      __syncthreads();
    }

    #pragma unroll
    for (int ci = 0; ci < 4; ++ci) {
      const int cg = cq + ci;
      const unsigned long long vb = MB[cg];
      const bool has1 = (vb >> 16) != 0ull;   // any valid token t >= 16?
      const bool has2 = (vb >> 32) != 0ull;   // any valid token t >= 32?

      f32x4 acc[2][2][3];
      #pragma unroll
      for (int bi = 0; bi < 2; ++bi)
        #pragma unroll
        for (int mi = 0; mi < 2; ++mi)
          #pragma unroll
          for (int ni = 0; ni < 3; ++ni) acc[bi][mi][ni] = f32x4{0.f, 0.f, 0.f, 0.f};

      __builtin_amdgcn_s_setprio(1);
      #pragma unroll
      for (int ks = 0; ks < 8; ++ks) {
        const int p = ks & 1, k = ks >> 1;
        bf16x8 bfv0 = *(const bf16x8*)(ldsb + lbase[0][p] + k * 128 + ci * 20480);
        #pragma unroll
        for (int bi = 0; bi < 2; ++bi)
          #pragma unroll
          for (int mi = 0; mi < 2; ++mi)
            acc[bi][mi][0] = __builtin_amdgcn_mfma_f32_16x16x32_bf16(a[bi][mi][ks], bfv0, acc[bi][mi][0], 0, 0, 0);
      }
      if (has1) {   // ~70% of c-rows: tokens in t=[16,32)
        #pragma unroll
        for (int ks = 0; ks < 8; ++ks) {
          const int p = ks & 1, k = ks >> 1;
          bf16x8 bfv1 = *(const bf16x8*)(ldsb + lbase[1][p] + k * 128 + ci * 20480);
          #pragma unroll
          for (int bi = 0; bi < 2; ++bi)
            #pragma unroll
            for (int mi = 0; mi < 2; ++mi)
              acc[bi][mi][1] = __builtin_amdgcn_mfma_f32_16x16x32_bf16(a[bi][mi][ks], bfv1, acc[bi][mi][1], 0, 0, 0);
        }
      }
      if (has2) {   // ~21% of c-rows: tokens in t=[32,40)
        #pragma unroll
        for (int ks = 0; ks < 8; ++ks) {
          const int p = ks & 1, k = ks >> 1;
          bf16x8 bfv2 = *(const bf16x8*)(ldsb + lbase[2][p] + k * 128 + ci * 20480);
          #pragma unroll
          for (int bi = 0; bi < 2; ++bi)
            #pragma unroll
            for (int mi = 0; mi < 2; ++mi)
              acc[bi][mi][2] = __builtin_amdgcn_mfma_f32_16x16x32_bf16(a[bi][mi][ks], bfv2, acc[bi][mi][2], 0, 0, 0);
        }
      }
      __builtin_amdgcn_s_setprio(0);

      const float inw = invt * NW[cg];
      bool val[3];
      #pragma unroll
      for (int ni = 0; ni < 3; ++ni) {
        int t = ni * 16 + lr;
        val[ni] = (t < 40) && ((vb >> t) & 1ull);
      }

      #pragma unroll
      for (int bi = 0; bi < 2; ++bi) {
        const int b = b0 + w * 2 + bi;

        // row-part: per-q max over valid t, then mean over 32 q.
        // ni>=1 contributions only exist when has1/has2 (else acc==0,val=false).
        float rp[2][4];
        #pragma unroll
        for (int mi = 0; mi < 2; ++mi)
          #pragma unroll
          for (int j = 0; j < 4; ++j) {
            float v = val[0] ? acc[bi][mi][0][j] : -2.0f;
            if (has1) {
              float v1 = val[1] ? acc[bi][mi][1][j] : -2.0f;
              v = fmaxf(v, v1);
            }
            if (has2) {
              float v2 = val[2] ? acc[bi][mi][2][j] : -2.0f;
              v = fmaxf(v, v2);
            }
            rp[mi][j] = max16(v);  // uniform over lr
          }
        float rsum = rp[0][0] + rp[0][1] + rp[0][2] + rp[0][3]
                   + rp[1][0] + rp[1][1] + rp[1][2] + rp[1][3];
        rsum = rowsum_to63(rsum);   // lane 63 holds the total

        // col-part: per-t max over 32 q, mean over valid t.
        // chains for ni=1/2 gated by the uniform flags (cp=0 when skipped).
        float cp0, cp1 = 0.f, cp2 = 0.f;
        {
          float m = fmaxf(fmaxf(fmaxf(acc[bi][0][0][0], acc[bi][0][0][1]),
                                fmaxf(acc[bi][0][0][2], acc[bi][0][0][3])),
                          fmaxf(fmaxf(acc[bi][1][0][0], acc[bi][1][0][1]),
                                fmaxf(acc[bi][1][0][2], acc[bi][1][0][3])));
          m = plmax16(m);
          m = plmax32(m);
          cp0 = val[0] ? m : 0.0f;
        }
        if (has1) {
          float m = fmaxf(fmaxf(fmaxf(acc[bi][0][1][0], acc[bi][0][1][1]),
                                fmaxf(acc[bi][0][1][2], acc[bi][0][1][3])),
                          fmaxf(fmaxf(acc[bi][1][1][0], acc[bi][1][1][1]),
                                fmaxf(acc[bi][1][1][2], acc[bi][1][1][3])));
          m = plmax16(m);
          m = plmax32(m);
          cp1 = val[1] ? m : 0.0f;
        }
        if (has2) {
          float m = fmaxf(fmaxf(fmaxf(acc[bi][0][2][0], acc[bi][0][2][1]),
                                fmaxf(acc[bi][0][2][2], acc[bi][0][2][3])),
                          fmaxf(fmaxf(acc[bi][1][2][0], acc[bi][1][2][1]),
                                fmaxf(acc[bi][1][2][2], acc[bi][1][2][3])));
          m = plmax16(m);
          m = plmax32(m);
          cp2 = val[2] ? m : 0.0f;
        }
        float csum = sum16(cp0 + cp1 + cp2);  // uniform per row

        float sv = rsum * s32 + csum * inw;
        if (l == 63) {
          S [(size_t)b  * 256 + cg] = sv;
          St[(size_t)cg * 256 + b ] = sv;
        }
      }
    }
  }
}

// ---------------- loss stage 1: per-b row/col LSE of S ----------------------
__global__ __launch_bounds__(256) void k_loss1(const float* __restrict__ S,
                                               const float* __restrict__ St,
                                               float* __restrict__ v) {
  __shared__ float lred[2][4], sred[2][4];
  const int b = blockIdx.x, j = threadIdx.x;
  const int w = j >> 6, l = j & 63;
  float s1v = S [(size_t)b * 256 + j];  // row b of S
  float s2v = St[(size_t)b * 256 + j];  // col b of S
  float m1 = s1v, m2 = s2v;
  #pragma unroll
  for (int m = 1; m < 64; m <<= 1) {
    m1 = fmaxf(m1, __shfl_xor(m1, m));
    m2 = fmaxf(m2, __shfl_xor(m2, m));
  }
  if (l == 0) { lred[0][w] = m1; lred[1][w] = m2; }
  __syncthreads();
  m1 = fmaxf(fmaxf(lred[0][0], lred[0][1]), fmaxf(lred[0][2], lred[0][3]));
  m2 = fmaxf(fmaxf(lred[1][0], lred[1][1]), fmaxf(lred[1][2], lred[1][3]));
  float e1 = expf(s1v - m1), e2 = expf(s2v - m2);
  #pragma unroll
  for (int m = 1; m < 64; m <<= 1) {
    e1 += __shfl_xor(e1, m);
    e2 += __shfl_xor(e2, m);
  }
  if (l == 0) { sred[0][w] = e1; sred[1][w] = e2; }
  __syncthreads();
  if (j == 0) {
    float s1 = sred[0][0] + sred[0][1] + sred[0][2] + sred[0][3];
    float s2 = sred[1][0] + sred[1][1] + sred[1][2] + sred[1][3];
    v[b] = (m1 + logf(s1)) + (m2 + logf(s2)) - 2.0f * S[(size_t)b * 257];
  }
}

// ---------------- loss stage 2: mean ---------------------------------------
__global__ __launch_bounds__(256) void k_loss2(const float* __restrict__ v,
                                               float* __restrict__ out) {
  __shared__ float r[4];
  const int j = threadIdx.x;
  float x = v[j];
  #pragma unroll
  for (int m = 1; m < 64; m <<= 1) x += __shfl_xor(x, m);
  if ((j & 63) == 0) r[j >> 6] = x;
  __syncthreads();
  if (j == 0) out[0] = (r[0] + r[1] + r[2] + r[3]) * (1.0f / 512.0f);
}

extern "C" void kernel_launch(void* const* d_in, const int* in_sizes, int n_in,
                              void* d_out, int out_size, void* d_ws, size_t ws_size,
                              hipStream_t stream) {
  const float* concept = (const float*)d_in[0];
  const float* text    = (const float*)d_in[1];
  const int*   tmask   = (const int*)d_in[2];
  const float* Wc      = (const float*)d_in[3];
  const float* bc      = (const float*)d_in[4];
  const float* Ww      = (const float*)d_in[5];
  const float* bw      = (const float*)d_in[6];
  const float* temp    = (const float*)d_in[7];
  float* out = (float*)d_out;
  char* ws = (char*)d_ws;

  // workspace layout (bytes), ~10.8 MB
  float*              Sm   = (float*)(ws + 0);                  // 256x256 f32
  float*              Stm  = (float*)(ws + 262144);             // 256x256 f32
  unsigned short*     Wctb = (unsigned short*)(ws + 524288);    // 256x768 bf16
  unsigned short*     Wwtb = (unsigned short*)(ws + 917504);    // 256x768 bf16
  unsigned short*     CFb  = (unsigned short*)(ws + 1310720);   // 8192x256 bf16
  unsigned short*     WFb  = (unsigned short*)(ws + 5505024);   // 10240x256 bf16
  unsigned long long* MBp  = (unsigned long long*)(ws + 10747904);
  float*              NWp  = (float*)(ws + 10749952);
  float*              Vb   = (float*)(ws + 10751104);           // 256 f32

  k_trw<<<384, 256, 0, stream>>>(Wc, Ww, tmask, Wctb, Wwtb, MBp, NWp);
  k_proj<<<576, 256, 0, stream>>>(concept, text, Wctb, Wwtb, bc, bw, CFb, WFb);
  dim3 pg(16, 16);
  k_pair<<<pg, 512, 0, stream>>>(CFb, WFb, MBp, NWp, temp, Sm, Stm);
  k_loss1<<<256, 256, 0, stream>>>(Sm, Stm, Vb);
  k_loss2<<<1, 256, 0, stream>>>(Vb, out);
}

// Round 17
// 108.294 us; speedup vs baseline: 1.0668x; 1.0668x over previous
//
#include <hip/hip_runtime.h>
#include <hip/hip_bf16.h>
#include <stdint.h>

// ALBEF contrastive loss: B=256, Q=32, L=40, VW=TW=768, D=256.
// S = sim_i2t/temp; sim_t2i = S^T, so loss = row-LSE + col-LSE of one S.

using f32x4  = __attribute__((ext_vector_type(4))) float;
using bf16x8 = __attribute__((ext_vector_type(8))) short;
typedef unsigned uint32x2 __attribute__((ext_vector_type(2)));

__device__ __forceinline__ short f2bf(float f) {
  union { float f; uint32_t u; } x; x.f = f;
  uint32_t r = x.u + 0x7FFFu + ((x.u >> 16) & 1u);  // RNE
  return (short)(r >> 16);
}

// pack 8 f32 -> 8 bf16 via v_cvt_pk_bf16_f32 (RNE, 2 elems/instr)
__device__ __forceinline__ bf16x8 pack8pk(float4 v0, float4 v1) {
  union { uint32_t u[4]; bf16x8 v; } r;
  asm("v_cvt_pk_bf16_f32 %0, %1, %2" : "=v"(r.u[0]) : "v"(v0.x), "v"(v0.y));
  asm("v_cvt_pk_bf16_f32 %0, %1, %2" : "=v"(r.u[1]) : "v"(v0.z), "v"(v0.w));
  asm("v_cvt_pk_bf16_f32 %0, %1, %2" : "=v"(r.u[2]) : "v"(v1.x), "v"(v1.y));
  asm("v_cvt_pk_bf16_f32 %0, %1, %2" : "=v"(r.u[3]) : "v"(v1.z), "v"(v1.w));
  return r.v;
}

// async global->LDS, 16B per lane; LDS dest = wave-uniform base + lane*16
__device__ __forceinline__ void gl_lds16(const unsigned short* g, unsigned short* l) {
  __builtin_amdgcn_global_load_lds(
      (const __attribute__((address_space(1))) void*)g,
      (__attribute__((address_space(3))) void*)l, 16, 0, 0);
}

// ---- DPP lane reductions (VALU pipe, not LDS) ----
template <int CTRL>
__device__ __forceinline__ float dppf(float x) {
  return __int_as_float(__builtin_amdgcn_update_dpp(
      0, __float_as_int(x), CTRL, 0xF, 0xF, true));
}
__device__ __forceinline__ float max16(float x) {  // max over 16-lane row
  x = fmaxf(x, dppf<0xB1>(x));
  x = fmaxf(x, dppf<0x4E>(x));
  x = fmaxf(x, dppf<0x141>(x));
  x = fmaxf(x, dppf<0x140>(x));
  return x;
}
__device__ __forceinline__ float sum16(float x) {  // sum over 16-lane row
  x += dppf<0xB1>(x);
  x += dppf<0x4E>(x);
  x += dppf<0x141>(x);
  x += dppf<0x140>(x);
  return x;
}
// row-uniform input -> lane 63 holds sum of the 4 row values (VALU only)
__device__ __forceinline__ float rowsum_to63(float x) {
  x += dppf<0x142>(x);   // ROW_BCAST15
  x += dppf<0x143>(x);   // ROW_BCAST31
  return x;              // lane 63 = r0+r1+r2+r3
}

// ---- cross-row element-wise combines on the VALU pipe (gfx950 permlane) ----
#if __has_builtin(__builtin_amdgcn_permlane16_swap)
__device__ __forceinline__ float plmax16(float x) {
  uint32x2 r = __builtin_amdgcn_permlane16_swap(__float_as_uint(x), __float_as_uint(x), false, false);
  return fmaxf(__uint_as_float(r[0]), __uint_as_float(r[1]));
}
#else
__device__ __forceinline__ float plmax16(float x) { return fmaxf(x, __shfl_xor(x, 16)); }
#endif
#if __has_builtin(__builtin_amdgcn_permlane32_swap)
__device__ __forceinline__ float plmax32(float x) {
  uint32x2 r = __builtin_amdgcn_permlane32_swap(__float_as_uint(x), __float_as_uint(x), false, false);
  return fmaxf(__uint_as_float(r[0]), __uint_as_float(r[1]));
}
#else
__device__ __forceinline__ float plmax32(float x) { return fmaxf(x, __shfl_xor(x, 32)); }
#endif

// ------------- W transpose+cvt via LDS tiles + mask preprocess (block 0) ----
__global__ __launch_bounds__(256) void k_trw(const float* __restrict__ Wc,
                                             const float* __restrict__ Ww,
                                             const int* __restrict__ tm,
                                             unsigned short* __restrict__ Wct,
                                             unsigned short* __restrict__ Wwt,
                                             unsigned long long* __restrict__ mb,
                                             float* __restrict__ nw) {
  __shared__ float tile[32][33];
  if (blockIdx.x == 0) {
    int b = threadIdx.x;  // 256 threads, one per batch row
    unsigned long long bits = 0ull;
    int sep = -1;
    #pragma unroll
    for (int t = 1; t < 40; ++t) {
      if (tm[b * 40 + t] > 0) { bits |= (1ull << t); sep = t; }
    }
    if (sep >= 0) bits &= ~(1ull << sep);
    mb[b] = bits;
    nw[b] = 1.0f / (float)__popcll(bits);
  }
  int blk = blockIdx.x;
  const float* W; unsigned short* O;
  if (blk < 192) { W = Wc; O = Wct; } else { W = Ww; O = Wwt; blk -= 192; }
  const int tk = blk >> 3, td = blk & 7;   // 24 k-tiles x 8 d-tiles
  const int k0 = tk * 32, d0 = td * 32;
  const int t = threadIdx.x;
  const int r = t >> 3, cq = (t & 7) * 4;
  float4 v = *(const float4*)(W + (size_t)(k0 + r) * 256 + d0 + cq);
  tile[r][cq] = v.x; tile[r][cq + 1] = v.y; tile[r][cq + 2] = v.z; tile[r][cq + 3] = v.w;
  __syncthreads();
  ushort4 o;
  o.x = (unsigned short)f2bf(tile[cq + 0][r]);
  o.y = (unsigned short)f2bf(tile[cq + 1][r]);
  o.z = (unsigned short)f2bf(tile[cq + 2][r]);
  o.w = (unsigned short)f2bf(tile[cq + 3][r]);
  *(ushort4*)(O + (size_t)(d0 + r) * 768 + k0 + cq) = o;
}

// ---------- merged proj GEMM + bias + l2norm, LDS-staged A -----------------
__global__ __launch_bounds__(256) void k_proj(const float* __restrict__ Xc,
                                              const float* __restrict__ Xt,
                                              const unsigned short* __restrict__ Wct,
                                              const unsigned short* __restrict__ Wwt,
                                              const float* __restrict__ bc,
                                              const float* __restrict__ bw,
                                              unsigned short* __restrict__ CFb,
                                              unsigned short* __restrict__ WFb) {
  __shared__ unsigned short As[32 * 768];  // 48 KB bf16, swizzled
  __shared__ float red[32][4];
  const int blk = blockIdx.x;
  const float* X; const unsigned short* Wtb; const float* bias;
  unsigned short* out; int m0;
  if (blk < 256) { X = Xc; Wtb = Wct; bias = bc; out = CFb; m0 = blk * 32; }
  else           { X = Xt; Wtb = Wwt; bias = bw; out = WFb; m0 = (blk - 256) * 32; }

  const int t = threadIdx.x;
  #pragma unroll
  for (int i = 0; i < 12; ++i) {
    int ch = i * 256 + t;
    int r = ch / 96, c = ch - r * 96;
    const float* p = X + (size_t)(m0 + r) * 768 + c * 8;
    bf16x8 v = pack8pk(*(const float4*)p, *(const float4*)(p + 4));
    *(bf16x8*)(&As[r * 768 + ((c ^ (r & 7)) * 8)]) = v;
  }
  __syncthreads();

  const int w = t >> 6, l = t & 63;
  const int lr = l & 15, lg = l >> 4;
  const int n0 = w * 64;

  f32x4 acc[2][4];
  #pragma unroll
  for (int mi = 0; mi < 2; ++mi)
    #pragma unroll
    for (int ni = 0; ni < 4; ++ni) acc[mi][ni] = f32x4{0.f, 0.f, 0.f, 0.f};

  const int r0 = lr, r1 = 16 + lr;

  #pragma unroll 4
  for (int ks = 0; ks < 24; ++ks) {
    const int c16 = ks * 4 + lg;
    bf16x8 a0 = *(const bf16x8*)(&As[r0 * 768 + ((c16 ^ (r0 & 7)) * 8)]);
    bf16x8 a1 = *(const bf16x8*)(&As[r1 * 768 + ((c16 ^ (r1 & 7)) * 8)]);
    bf16x8 bb[4];
    #pragma unroll
    for (int ni = 0; ni < 4; ++ni)
      bb[ni] = *(const bf16x8*)(Wtb + (size_t)(n0 + ni * 16 + lr) * 768 + ks * 32 + lg * 8);
    #pragma unroll
    for (int ni = 0; ni < 4; ++ni)
      acc[0][ni] = __builtin_amdgcn_mfma_f32_16x16x32_bf16(a0, bb[ni], acc[0][ni], 0, 0, 0);
    #pragma unroll
    for (int ni = 0; ni < 4; ++ni)
      acc[1][ni] = __builtin_amdgcn_mfma_f32_16x16x32_bf16(a1, bb[ni], acc[1][ni], 0, 0, 0);
  }

  float bv[4];
  #pragma unroll
  for (int ni = 0; ni < 4; ++ni) bv[ni] = bias[n0 + ni * 16 + lr];

  float ss[2][4];
  #pragma unroll
  for (int mi = 0; mi < 2; ++mi)
    #pragma unroll
    for (int j = 0; j < 4; ++j) {
      float s = 0.f;
      #pragma unroll
      for (int ni = 0; ni < 4; ++ni) {
        acc[mi][ni][j] += bv[ni];
        s += acc[mi][ni][j] * acc[mi][ni][j];
      }
      ss[mi][j] = s;
    }
  #pragma unroll
  for (int m = 1; m <= 8; m <<= 1)
    #pragma unroll
    for (int mi = 0; mi < 2; ++mi)
      #pragma unroll
      for (int j = 0; j < 4; ++j)
        ss[mi][j] += __shfl_xor(ss[mi][j], m);
  if (lr == 0) {
    #pragma unroll
    for (int mi = 0; mi < 2; ++mi)
      #pragma unroll
      for (int j = 0; j < 4; ++j)
        red[mi * 16 + lg * 4 + j][w] = ss[mi][j];
  }
  __syncthreads();
  #pragma unroll
  for (int mi = 0; mi < 2; ++mi)
    #pragma unroll
    for (int j = 0; j < 4; ++j) {
      int r = mi * 16 + lg * 4 + j;
      float sc = rsqrtf(red[r][0] + red[r][1] + red[r][2] + red[r][3]);
      #pragma unroll
      for (int ni = 0; ni < 4; ++ni)
        out[(size_t)(m0 + r) * 256 + n0 + ni * 16 + lr] =
            (unsigned short)f2bf(acc[mi][ni][j] * sc);
    }
}

// ------------- pairwise sim: 16 b x 16 c per block, 2 b's per wave ---------
// R15 structure (best measured): main ks loop reads TWO B-frags (ni=0,1) and
// issues 8 MFMAs — wide body keeps ds_read latency hidden. ni=2 block gated
// by has2 (~79% skip). Only NEW vs R15: the tail's cp2 DPP chain is also
// gated by has2 (skipped chain's exact value is 0).
__global__ __launch_bounds__(512, 2) void k_pair(const unsigned short* __restrict__ CF,
                                                 const unsigned short* __restrict__ WF,
                                                 const unsigned long long* __restrict__ MB,
                                                 const float* __restrict__ NW,
                                                 const float* __restrict__ TEMP,
                                                 float* __restrict__ S,
                                                 float* __restrict__ St) {
  __shared__ unsigned short wfs[40960];  // 4 tiles x [40][256] bf16, swizzled
  const int tid = threadIdx.x;
  const int w = tid >> 6, l = tid & 63;
  const int lr = l & 15, lg = l >> 4;
  const int b0 = blockIdx.x * 16, c0 = blockIdx.y * 16;
  const float invt = 1.0f / TEMP[0];
  const float s32 = invt * 0.03125f;

  // stage panel: 8 waves; wave w stages tile (w>>1) half (w&1): 10 x 1KB
  const int sti = w >> 1, sth = w & 1;
  {
    const int cq = c0;
    #pragma unroll
    for (int j = 0; j < 10; ++j) {
      int t = sth * 20 + j * 2 + (l >> 5), sl = l & 31;
      gl_lds16(WF + ((size_t)(cq + sti) * 40 + t) * 256 + ((sl ^ (t & 7)) * 8),
               &wfs[sti * 10240 + sth * 5120 + j * 512]);
    }
  }

  // hoist A frags for this wave's two b's (L2-resident CF): 128 VGPRs
  bf16x8 a[2][2][8];
  #pragma unroll
  for (int bi = 0; bi < 2; ++bi) {
    const int b = b0 + w * 2 + bi;
    #pragma unroll
    for (int mi = 0; mi < 2; ++mi)
      #pragma unroll
      for (int ks = 0; ks < 8; ++ks)
        a[bi][mi][ks] = *(const bf16x8*)(CF + (size_t)(b * 32 + mi * 16 + lr) * 256 + (ks * 4 + lg) * 8);
  }

  // 6 swizzled LDS base offsets (bytes); per-read immediate = k*128 + ci*20480.
  int lbase[3][2];
  #pragma unroll
  for (int ni = 0; ni < 3; ++ni) {
    int t = ni * 16 + lr; if (t > 39) t = 39;
    int x = t & 7;
    #pragma unroll
    for (int p = 0; p < 2; ++p)
      lbase[ni][p] = t * 512 + ((lg ^ (x & 3)) * 16) + ((p ^ ((x >> 2) & 1)) * 64);
  }
  const char* ldsb = (const char*)wfs;

  asm volatile("s_waitcnt vmcnt(0)" ::: "memory");
  __syncthreads();

  #pragma unroll 1
  for (int pn = 0; pn < 4; ++pn) {
    const int cq = c0 + pn * 4;
    if (pn > 0) {
      __syncthreads();   // all waves done reading previous panel
      #pragma unroll
      for (int j = 0; j < 10; ++j) {
        int t = sth * 20 + j * 2 + (l >> 5), sl = l & 31;
        gl_lds16(WF + ((size_t)(cq + sti) * 40 + t) * 256 + ((sl ^ (t & 7)) * 8),
                 &wfs[sti * 10240 + sth * 5120 + j * 512]);
      }
      asm volatile("s_waitcnt vmcnt(0)" ::: "memory");
      __syncthreads();
    }

    #pragma unroll
    for (int ci = 0; ci < 4; ++ci) {
      const int cg = cq + ci;
      const unsigned long long vb = MB[cg];
      const bool has2 = (vb >> 32) != 0ull;   // any valid token t >= 32?

      f32x4 acc[2][2][3];
      #pragma unroll
      for (int bi = 0; bi < 2; ++bi)
        #pragma unroll
        for (int mi = 0; mi < 2; ++mi)
          #pragma unroll
          for (int ni = 0; ni < 3; ++ni) acc[bi][mi][ni] = f32x4{0.f, 0.f, 0.f, 0.f};

      __builtin_amdgcn_s_setprio(1);
      #pragma unroll
      for (int ks = 0; ks < 8; ++ks) {
        const int p = ks & 1, k = ks >> 1;
        bf16x8 bfv0 = *(const bf16x8*)(ldsb + lbase[0][p] + k * 128 + ci * 20480);
        bf16x8 bfv1 = *(const bf16x8*)(ldsb + lbase[1][p] + k * 128 + ci * 20480);
        #pragma unroll
        for (int bi = 0; bi < 2; ++bi)
          #pragma unroll
          for (int mi = 0; mi < 2; ++mi) {
            acc[bi][mi][0] = __builtin_amdgcn_mfma_f32_16x16x32_bf16(a[bi][mi][ks], bfv0, acc[bi][mi][0], 0, 0, 0);
            acc[bi][mi][1] = __builtin_amdgcn_mfma_f32_16x16x32_bf16(a[bi][mi][ks], bfv1, acc[bi][mi][1], 0, 0, 0);
          }
      }
      if (has2) {   // ~21% of c-rows: tokens in t=[32,39]
        #pragma unroll
        for (int ks = 0; ks < 8; ++ks) {
          const int p = ks & 1, k = ks >> 1;
          bf16x8 bfv2 = *(const bf16x8*)(ldsb + lbase[2][p] + k * 128 + ci * 20480);
          #pragma unroll
          for (int bi = 0; bi < 2; ++bi)
            #pragma unroll
            for (int mi = 0; mi < 2; ++mi)
              acc[bi][mi][2] = __builtin_amdgcn_mfma_f32_16x16x32_bf16(a[bi][mi][ks], bfv2, acc[bi][mi][2], 0, 0, 0);
        }
      }
      __builtin_amdgcn_s_setprio(0);

      const float inw = invt * NW[cg];
      bool val[3];
      #pragma unroll
      for (int ni = 0; ni < 3; ++ni) {
        int t = ni * 16 + lr;
        val[ni] = (t < 40) && ((vb >> t) & 1ull);
      }

      #pragma unroll
      for (int bi = 0; bi < 2; ++bi) {
        const int b = b0 + w * 2 + bi;

        // row-part: per-q max over t (invalid t -> -2), then mean over 32 q
        float rp[2][4];
        #pragma unroll
        for (int mi = 0; mi < 2; ++mi)
          #pragma unroll
          for (int j = 0; j < 4; ++j) {
            float v0 = val[0] ? acc[bi][mi][0][j] : -2.0f;
            float v1 = val[1] ? acc[bi][mi][1][j] : -2.0f;
            float v2 = val[2] ? acc[bi][mi][2][j] : -2.0f;
            rp[mi][j] = max16(fmaxf(fmaxf(v0, v1), v2));  // uniform over lr
          }
        float rsum = rp[0][0] + rp[0][1] + rp[0][2] + rp[0][3]
                   + rp[1][0] + rp[1][1] + rp[1][2] + rp[1][3];
        rsum = rowsum_to63(rsum);   // lane 63 holds the total

        // col-part: per-t max over 32 q, mean over valid t.
        // cp2's chain gated by has2 (skipped chain's exact value is 0).
        float cp0, cp1, cp2 = 0.f;
        {
          float m = fmaxf(fmaxf(fmaxf(acc[bi][0][0][0], acc[bi][0][0][1]),
                                fmaxf(acc[bi][0][0][2], acc[bi][0][0][3])),
                          fmaxf(fmaxf(acc[bi][1][0][0], acc[bi][1][0][1]),
                                fmaxf(acc[bi][1][0][2], acc[bi][1][0][3])));
          m = plmax16(m);
          m = plmax32(m);
          cp0 = val[0] ? m : 0.0f;
        }
        {
          float m = fmaxf(fmaxf(fmaxf(acc[bi][0][1][0], acc[bi][0][1][1]),
                                fmaxf(acc[bi][0][1][2], acc[bi][0][1][3])),
                          fmaxf(fmaxf(acc[bi][1][1][0], acc[bi][1][1][1]),
                                fmaxf(acc[bi][1][1][2], acc[bi][1][1][3])));
          m = plmax16(m);
          m = plmax32(m);
          cp1 = val[1] ? m : 0.0f;
        }
        if (has2) {
          float m = fmaxf(fmaxf(fmaxf(acc[bi][0][2][0], acc[bi][0][2][1]),
                                fmaxf(acc[bi][0][2][2], acc[bi][0][2][3])),
                          fmaxf(fmaxf(acc[bi][1][2][0], acc[bi][1][2][1]),
                                fmaxf(acc[bi][1][2][2], acc[bi][1][2][3])));
          m = plmax16(m);
          m = plmax32(m);
          cp2 = val[2] ? m : 0.0f;
        }
        float csum = sum16(cp0 + cp1 + cp2);  // uniform per row

        float sv = rsum * s32 + csum * inw;
        if (l == 63) {
          S [(size_t)b  * 256 + cg] = sv;
          St[(size_t)cg * 256 + b ] = sv;
        }
      }
    }
  }
}

// ---------------- loss stage 1: per-b row/col LSE of S ----------------------
__global__ __launch_bounds__(256) void k_loss1(const float* __restrict__ S,
                                               const float* __restrict__ St,
                                               float* __restrict__ v) {
  __shared__ float lred[2][4], sred[2][4];
  const int b = blockIdx.x, j = threadIdx.x;
  const int w = j >> 6, l = j & 63;
  float s1v = S [(size_t)b * 256 + j];  // row b of S
  float s2v = St[(size_t)b * 256 + j];  // col b of S
  float m1 = s1v, m2 = s2v;
  #pragma unroll
  for (int m = 1; m < 64; m <<= 1) {
    m1 = fmaxf(m1, __shfl_xor(m1, m));
    m2 = fmaxf(m2, __shfl_xor(m2, m));
  }
  if (l == 0) { lred[0][w] = m1; lred[1][w] = m2; }
  __syncthreads();
  m1 = fmaxf(fmaxf(lred[0][0], lred[0][1]), fmaxf(lred[0][2], lred[0][3]));
  m2 = fmaxf(fmaxf(lred[1][0], lred[1][1]), fmaxf(lred[1][2], lred[1][3]));
  float e1 = expf(s1v - m1), e2 = expf(s2v - m2);
  #pragma unroll
  for (int m = 1; m < 64; m <<= 1) {
    e1 += __shfl_xor(e1, m);
    e2 += __shfl_xor(e2, m);
  }
  if (l == 0) { sred[0][w] = e1; sred[1][w] = e2; }
  __syncthreads();
  if (j == 0) {
    float s1 = sred[0][0] + sred[0][1] + sred[0][2] + sred[0][3];
    float s2 = sred[1][0] + sred[1][1] + sred[1][2] + sred[1][3];
    v[b] = (m1 + logf(s1)) + (m2 + logf(s2)) - 2.0f * S[(size_t)b * 257];
  }
}

// ---------------- loss stage 2: mean ---------------------------------------
__global__ __launch_bounds__(256) void k_loss2(const float* __restrict__ v,
                                               float* __restrict__ out) {
  __shared__ float r[4];
  const int j = threadIdx.x;
  float x = v[j];
  #pragma unroll
  for (int m = 1; m < 64; m <<= 1) x += __shfl_xor(x, m);
  if ((j & 63) == 0) r[j >> 6] = x;
  __syncthreads();
  if (j == 0) out[0] = (r[0] + r[1] + r[2] + r[3]) * (1.0f / 512.0f);
}

extern "C" void kernel_launch(void* const* d_in, const int* in_sizes, int n_in,
                              void* d_out, int out_size, void* d_ws, size_t ws_size,
                              hipStream_t stream) {
  const float* concept = (const float*)d_in[0];
  const float* text    = (const float*)d_in[1];
  const int*   tmask   = (const int*)d_in[2];
  const float* Wc      = (const float*)d_in[3];
  const float* bc      = (const float*)d_in[4];
  const float* Ww      = (const float*)d_in[5];
  const float* bw      = (const float*)d_in[6];
  const float* temp    = (const float*)d_in[7];
  float* out = (float*)d_out;
  char* ws = (char*)d_ws;

  // workspace layout (bytes), ~10.8 MB
  float*              Sm   = (float*)(ws + 0);                  // 256x256 f32
  float*              Stm  = (float*)(ws + 262144);             // 256x256 f32
  unsigned short*     Wctb = (unsigned short*)(ws + 524288);    // 256x768 bf16
  unsigned short*     Wwtb = (unsigned short*)(ws + 917504);    // 256x768 bf16
  unsigned short*     CFb  = (unsigned short*)(ws + 1310720);   // 8192x256 bf16
  unsigned short*     WFb  = (unsigned short*)(ws + 5505024);   // 10240x256 bf16
  unsigned long long* MBp  = (unsigned long long*)(ws + 10747904);
  float*              NWp  = (float*)(ws + 10749952);
  float*              Vb   = (float*)(ws + 10751104);           // 256 f32

  k_trw<<<384, 256, 0, stream>>>(Wc, Ww, tmask, Wctb, Wwtb, MBp, NWp);
  k_proj<<<576, 256, 0, stream>>>(concept, text, Wctb, Wwtb, bc, bw, CFb, WFb);
  dim3 pg(16, 16);
  k_pair<<<pg, 512, 0, stream>>>(CFb, WFb, MBp, NWp, temp, Sm, Stm);
  k_loss1<<<256, 256, 0, stream>>>(Sm, Stm, Vb);
  k_loss2<<<1, 256, 0, stream>>>(Vb, out);
}